// Round 11
// baseline (998.530 us; speedup 1.0000x reference)
//
#include <hip/hip_runtime.h>

typedef _Float16 half_t;
typedef __attribute__((ext_vector_type(4))) _Float16 half4;
typedef __attribute__((ext_vector_type(8))) _Float16 half8;
typedef __attribute__((ext_vector_type(2))) float f32x2;
typedef __attribute__((ext_vector_type(4))) float f32x4;

#define NB 32
#define NH 128
#define NW 128
#define NOH 122
#define NOW 122
#define NOC 512
#define KPAD 64
#define REPEAT 4   // DIAGNOSTIC: re-run the compute+flush to surface k_main in
                   // rocprof top-5 (fills are ~600us; 4x272us beats them).
                   // Writes identical values each rep -> deterministic/correct.

// ws layout (bytes):
//   gh: [32][128][128] half  @ 0         (1048576)
//   Wh: [512][64]      half  @ 1048576   (65536)   t = kh*8+kw, zero-padded
//   w2: [512]          float @ 1114112   (2048)
//   x2: [32][122][122] float @ 1116160   (1905152 + 128 slack)
//   Sg: [32][128][122] float @ 3021440   (1998848)

__global__ __launch_bounds__(256) void k_gray(const float* __restrict__ x,
                                              half_t* __restrict__ gh) {
    int t = blockIdx.x * 256 + threadIdx.x;   // one thread = 4 pixels
    if (t >= NB * NH * NW / 4) return;
    int b = t >> 12;
    int pix4 = t & 4095;
    const float* xb = x + (size_t)b * 3 * 16384 + pix4 * 4;
    f32x4 r = *(const f32x4*)xb;
    f32x4 g = *(const f32x4*)(xb + 16384);
    f32x4 bl = *(const f32x4*)(xb + 32768);
    half4 o;
#pragma unroll
    for (int i = 0; i < 4; ++i)
        o[i] = (half_t)(0.2989f * r[i] + 0.587f * g[i] + 0.114f * bl[i]);
    *(half4*)(gh + (size_t)t * 4) = o;
}

__global__ __launch_bounds__(256) void k_w(const float* __restrict__ w,
                                           half_t* __restrict__ Wh,
                                           float* __restrict__ w2) {
    int o = blockIdx.x * 256 + threadIdx.x;
    if (o >= NOC) return;
    float s = 0.f;
    for (int t = 0; t < KPAD; ++t) {
        int kh = t >> 3, kw = t & 7;
        float v = (kh < 7 && kw < 7) ? w[o * 49 + kh * 7 + kw] : 0.f;
        half_t h = (half_t)v;
        Wh[o * KPAD + t] = h;
        float f = (float)h;
        s += f * f;
    }
    w2[o] = s;
}

// Sg[b][h][p] = sum_{kw<7} gh[b][h][p+kw]^2   (separable pass 1)
__global__ __launch_bounds__(256) void k_rs(const half_t* __restrict__ gh,
                                            float* __restrict__ Sg) {
    int t = blockIdx.x * 256 + threadIdx.x;
    if (t >= NB * NH * NOW) return;
    int b = t / (NH * NOW);
    int rem = t - b * (NH * NOW);
    int h = rem / NOW;
    int p = rem - h * NOW;
    const half_t* g = gh + ((size_t)b * NH + h) * NW + p;
    float s = 0.f;
#pragma unroll
    for (int kw = 0; kw < 7; ++kw) {
        float v = (float)g[kw];
        s += v * v;
    }
    Sg[t] = s;
}

// x2[b][oh][p] = sum_{kh<7} Sg[b][oh+kh][p]   (separable pass 2)
__global__ __launch_bounds__(256) void k_x2(const float* __restrict__ Sg,
                                            float* __restrict__ x2) {
    int t = blockIdx.x * 256 + threadIdx.x;
    if (t >= NB * NOH * NOW) return;
    int b = t / (NOH * NOW);
    int rem = t - b * (NOH * NOW);
    int oh = rem / NOW;
    int p = rem - oh * NOW;
    const float* s0 = Sg + ((size_t)b * NH + oh) * NOW + p;
    float s = 0.f;
#pragma unroll
    for (int kh = 0; kh < 7; ++kh) s += s0[kh * NOW];
    x2[t] = s;
}

// v11 = r7 structure (best known: 32 o x 4 oh, 1952B NT chunks, ohq-fastest)
// wrapped in a REPEAT loop for counter visibility. Identical output.
__global__ __launch_bounds__(256, 2) void k_main(const half_t* __restrict__ gh,
                                                 const half_t* __restrict__ Wh,
                                                 const float* __restrict__ w2,
                                                 const float* __restrict__ x2,
                                                 const float* __restrict__ stdp,
                                                 float* __restrict__ out) {
    const int ohq = blockIdx.x;   // 0..30 (oh quad, fastest-varying)
    const int fgg = blockIdx.y;   // 0..15 (32 filters)
    const int b   = blockIdx.z;   // 0..31
    const int oh0 = (ohq * 4 > NOH - 4) ? (NOH - 4) : (ohq * 4);  // 118 max

    __shared__ half_t gS[11][136];      // rows oh0..oh0+10 (clamped), cols>=128 zero
    __shared__ float  outT[32 * 488];   // [o_local][lo*122 + p] == global layout

    const int tid  = threadIdx.x;
    const int wave = tid >> 6;
    const int lane = tid & 63;
    const int col  = lane & 15;
    const int kq   = lane >> 4;
    const int n0   = wave * 32;

    for (int idx = tid; idx < 11 * 136; idx += 256) {
        int r = idx / 136;
        int c = idx - r * 136;
        int row = oh0 + r;
        if (row > NH - 1) row = NH - 1;
        gS[r][c] = (c < 128) ? gh[((size_t)b * NH + row) * NW + c] : (half_t)0.f;
    }

    half8 wfrag[2][2];
#pragma unroll
    for (int ni = 0; ni < 2; ++ni)
#pragma unroll
        for (int ks = 0; ks < 2; ++ks)
            wfrag[ni][ks] = *(const half8*)(Wh + ((size_t)(fgg * 32 + ni * 16 + col) * KPAD
                                                  + (ks * 4 + kq) * 8));
    float w2c[2];
#pragma unroll
    for (int ni = 0; ni < 2; ++ni) w2c[ni] = w2[fgg * 32 + ni * 16 + col];

    const float sv = stdp[0];
    const float inv2s2 = 0.5f / (sv * sv);

    __syncthreads();

    for (int rep = 0; rep < REPEAT; ++rep) {
#pragma unroll
        for (int lo = 0; lo < 4; ++lo) {
            const int oh = oh0 + lo;

            half8 afrag[2][2];
#pragma unroll
            for (int mi = 0; mi < 2; ++mi) {
                const int p = n0 + mi * 16 + col;
#pragma unroll
                for (int ks = 0; ks < 2; ++ks) {
                    const half_t* src = &gS[lo + ks * 4 + kq][p];
                    half8 v;
#pragma unroll
                    for (int i = 0; i < 8; ++i) v[i] = src[i];
                    afrag[mi][ks] = v;
                }
            }

            f32x4 acc[2][2];
#pragma unroll
            for (int mi = 0; mi < 2; ++mi)
#pragma unroll
                for (int ni = 0; ni < 2; ++ni) {
                    f32x4 z = {0.f, 0.f, 0.f, 0.f};
                    acc[mi][ni] = z;
                }

#pragma unroll
            for (int ks = 0; ks < 2; ++ks)
#pragma unroll
                for (int mi = 0; mi < 2; ++mi)
#pragma unroll
                    for (int ni = 0; ni < 2; ++ni)
                        acc[mi][ni] = __builtin_amdgcn_mfma_f32_16x16x32_f16(
                            afrag[mi][ks], wfrag[ni][ks], acc[mi][ni], 0, 0, 0);

            const size_t rowBase = ((size_t)b * NOH + oh) * NOW;

#pragma unroll
            for (int mi = 0; mi < 2; ++mi) {
                const int p0 = n0 + mi * 16 + kq * 4;
                if (p0 >= NOW) continue;                   // p0==124 idle
                const f32x4 x2v = *(const f32x4*)(x2 + rowBase + p0);
                const bool full = (p0 + 3 < NOW);          // p0==120 -> 2 valid
#pragma unroll
                for (int ni = 0; ni < 2; ++ni) {
                    f32x4 res;
#pragma unroll
                    for (int r = 0; r < 4; ++r) {
                        float sq = fmaxf(fmaf(-2.f, acc[mi][ni][r], x2v[r] + w2c[ni]), 0.f);
                        res[r] = __expf(-sq * inv2s2);
                    }
                    float* dst = &outT[(ni * 16 + col) * 488 + lo * 122 + p0];
                    f32x2 lo2 = {res[0], res[1]};
                    *(f32x2*)dst = lo2;
                    if (full) {
                        f32x2 hi2 = {res[2], res[3]};
                        *(f32x2*)(dst + 2) = hi2;
                    }
                }
            }
        }

        __syncthreads();

        // Flush: 32 chunks of 1952B contiguous NT stores.
        if (lane < 61) {
            const size_t base = (((size_t)b * NOC + fgg * 32) * NOH + oh0) * NOW;
#pragma unroll 4
            for (int c = 0; c < 8; ++c) {
                const int o = wave * 8 + c;
                float* gdst = out + base + (size_t)o * NOH * NOW + lane * 4;
#pragma unroll
                for (int j = 0; j < 2; ++j) {
                    f32x4 v = *(const f32x4*)&outT[o * 488 + j * 244 + lane * 4];
                    __builtin_nontemporal_store(v, (f32x4*)(gdst + j * 244));
                }
            }
        }

        __syncthreads();   // protect outT before next rep overwrites it
    }
}

extern "C" void kernel_launch(void* const* d_in, const int* in_sizes, int n_in,
                              void* d_out, int out_size, void* d_ws, size_t ws_size,
                              hipStream_t stream) {
    const float* x    = (const float*)d_in[0];
    const float* w    = (const float*)d_in[1];
    const float* stdp = (const float*)d_in[2];
    float* out = (float*)d_out;

    char* ws = (char*)d_ws;
    half_t* gh = (half_t*)ws;
    half_t* Wh = (half_t*)(ws + 1048576);
    float*  w2 = (float*)(ws + 1114112);
    float*  x2 = (float*)(ws + 1116160);
    float*  Sg = (float*)(ws + 3021440);

    k_gray<<<(NB * NH * NW / 4 + 255) / 256, 256, 0, stream>>>(x, gh);
    k_w<<<(NOC + 255) / 256, 256, 0, stream>>>(w, Wh, w2);
    k_rs<<<(NB * NH * NOW + 255) / 256, 256, 0, stream>>>(gh, Sg);
    k_x2<<<(NB * NOH * NOW + 255) / 256, 256, 0, stream>>>(Sg, x2);

    dim3 grid(31, 16, NB);
    k_main<<<grid, 256, 0, stream>>>(gh, Wh, w2, x2, stdp, out);
}

// Round 12
// 303.192 us; speedup vs baseline: 3.2934x; 3.2934x over previous
//
#include <hip/hip_runtime.h>

typedef _Float16 half_t;
typedef __attribute__((ext_vector_type(4))) _Float16 half4;
typedef __attribute__((ext_vector_type(8))) _Float16 half8;
typedef __attribute__((ext_vector_type(2))) float f32x2;
typedef __attribute__((ext_vector_type(4))) float f32x4;

#define NB 32
#define NH 128
#define NW 128
#define NOH 122
#define NOW 122
#define NOC 512
#define KPAD 64
#define NPIX (NB * NH * NW)   // 524288 halfs
#define OSTR 492              // outT row stride (floats): 492%32=12 -> no bank
                              // conflict on epilogue writes; 1968B row = 16B mult

// ws layout (bytes):
//   gh:  [32][128][128] half   @ 0         (1048576)
//   Wh:  [512][64]      half   @ 1048576   (65536)   t = kh*8+kw, zero-padded
//   w2:  [512]          float  @ 1114112   (2048)
//   x2:  [32][122][122] float  @ 1116160   (1905152 + 128 slack)
//   Sg:  [32][128][122] float  @ 3021440   (1998848)
//   ghs: [8][524288]    half   @ 5020288   (8388608)  ghs[s][j] = gh[j+s]

__global__ __launch_bounds__(256) void k_gray(const float* __restrict__ x,
                                              half_t* __restrict__ gh) {
    int t = blockIdx.x * 256 + threadIdx.x;   // one thread = 4 pixels
    if (t >= NPIX / 4) return;
    int b = t >> 12;
    int pix4 = t & 4095;
    const float* xb = x + (size_t)b * 3 * 16384 + pix4 * 4;
    f32x4 r = *(const f32x4*)xb;
    f32x4 g = *(const f32x4*)(xb + 16384);
    f32x4 bl = *(const f32x4*)(xb + 32768);
    half4 o;
#pragma unroll
    for (int i = 0; i < 4; ++i)
        o[i] = (half_t)(0.2989f * r[i] + 0.587f * g[i] + 0.114f * bl[i]);
    *(half4*)(gh + (size_t)t * 4) = o;
}

__global__ __launch_bounds__(256) void k_w(const float* __restrict__ w,
                                           half_t* __restrict__ Wh,
                                           float* __restrict__ w2) {
    int o = blockIdx.x * 256 + threadIdx.x;
    if (o >= NOC) return;
    float s = 0.f;
    for (int t = 0; t < KPAD; ++t) {
        int kh = t >> 3, kw = t & 7;
        float v = (kh < 7 && kw < 7) ? w[o * 49 + kh * 7 + kw] : 0.f;
        half_t h = (half_t)v;
        Wh[o * KPAD + t] = h;
        float f = (float)h;
        s += f * f;
    }
    w2[o] = s;
}

// 8 shifted copies of gh for aligned im2col fragment loads.
__global__ __launch_bounds__(256) void k_shift(const half_t* __restrict__ gh,
                                               half_t* __restrict__ ghs) {
    int t = blockIdx.x * 256 + threadIdx.x;   // NPIX/8 threads, 8 halfs each
    if (t >= NPIX / 8) return;
    const half8* g8 = (const half8*)gh;
    half8 a0 = g8[t];
    half8 a1 = g8[t + 1];   // last thread reads into Wh region (finite, x0 taps)
#pragma unroll
    for (int s = 0; s < 8; ++s) {
        half8 v;
#pragma unroll
        for (int i = 0; i < 8; ++i)
            v[i] = (i + s < 8) ? a0[i + s] : a1[i + s - 8];
        *(half8*)(ghs + (size_t)s * NPIX + (size_t)t * 8) = v;
    }
}

// Sg[b][h][p] = sum_{kw<7} gh[b][h][p+kw]^2   (separable pass 1)
__global__ __launch_bounds__(256) void k_rs(const half_t* __restrict__ gh,
                                            float* __restrict__ Sg) {
    int t = blockIdx.x * 256 + threadIdx.x;
    if (t >= NB * NH * NOW) return;
    int b = t / (NH * NOW);
    int rem = t - b * (NH * NOW);
    int h = rem / NOW;
    int p = rem - h * NOW;
    const half_t* g = gh + ((size_t)b * NH + h) * NW + p;
    float s = 0.f;
#pragma unroll
    for (int kw = 0; kw < 7; ++kw) {
        float v = (float)g[kw];
        s += v * v;
    }
    Sg[t] = s;
}

// x2[b][oh][p] = sum_{kh<7} Sg[b][oh+kh][p]   (separable pass 2)
__global__ __launch_bounds__(256) void k_x2(const float* __restrict__ Sg,
                                            float* __restrict__ x2) {
    int t = blockIdx.x * 256 + threadIdx.x;
    if (t >= NB * NOH * NOW) return;
    int b = t / (NOH * NOW);
    int rem = t - b * (NOH * NOW);
    int oh = rem / NOW;
    int p = rem - oh * NOW;
    const float* s0 = Sg + ((size_t)b * NH + oh) * NOW + p;
    float s = 0.f;
#pragma unroll
    for (int kh = 0; kh < 7; ++kh) s += s0[kh * NOW];
    x2[t] = s;
}

// v12 main = r7 flush structure (32 o x 4 oh, monolithic 1952B NT chunks,
// ohq-fastest grid) + r9 A-path (aligned global dwordx4 from shifted copies;
// no gS, no gather, no staging barrier) + conflict-free outT stride 492.
__global__ __launch_bounds__(256) void k_main(const half_t* __restrict__ ghs,
                                              const half_t* __restrict__ Wh,
                                              const float* __restrict__ w2,
                                              const float* __restrict__ x2,
                                              const float* __restrict__ stdp,
                                              float* __restrict__ out) {
    const int ohq = blockIdx.x;   // 0..30 (oh quad, fastest-varying)
    const int fgg = blockIdx.y;   // 0..15 (32 filters)
    const int b   = blockIdx.z;   // 0..31
    const int oh0 = (ohq * 4 > NOH - 4) ? (NOH - 4) : (ohq * 4);  // 118 max

    __shared__ float outT[32 * OSTR];   // [o_local][lo*122 + p], stride 492

    const int tid  = threadIdx.x;
    const int wave = tid >> 6;
    const int lane = tid & 63;
    const int col  = lane & 15;
    const int kq   = lane >> 4;
    const int n0   = wave * 32;

    // Shifted-copy selection: p = n0+mi*16+col -> shift s = col&7 (lane-const).
    const int s = col & 7;
    const half_t* gsh = ghs + (size_t)s * NPIX;
    const int pb0 = n0 + (col & 8);       // aligned base column (add mi*16)

    // B (weights): o = fgg*32 + ni*16 + col, elem i -> tap (ks*4+kq)*8 + i.
    half8 wfrag[2][2];
#pragma unroll
    for (int ni = 0; ni < 2; ++ni)
#pragma unroll
        for (int ks = 0; ks < 2; ++ks)
            wfrag[ni][ks] = *(const half8*)(Wh + ((size_t)(fgg * 32 + ni * 16 + col) * KPAD
                                                  + (ks * 4 + kq) * 8));
    float w2c[2];
#pragma unroll
    for (int ni = 0; ni < 2; ++ni) w2c[ni] = w2[fgg * 32 + ni * 16 + col];

    const float sv = stdp[0];
    const float inv2s2 = 0.5f / (sv * sv);

#pragma unroll
    for (int lo = 0; lo < 4; ++lo) {
        const int oh = oh0 + lo;

        // A (window): aligned 16B loads from the shifted copy; elem i =
        // gray[row][p+i] (linear). Row 128 clamps to 127 (only zero-weight
        // kh==7 taps reach it); col overflow only meets kw==7 (zero weight).
        half8 afrag[2][2];
#pragma unroll
        for (int mi = 0; mi < 2; ++mi) {
#pragma unroll
            for (int ks = 0; ks < 2; ++ks) {
                int row = oh + ks * 4 + kq;
                row = (row > NH - 1) ? (NH - 1) : row;
                const size_t flat = ((size_t)(b * NH + row)) * NW + pb0 + mi * 16;
                afrag[mi][ks] = *(const half8*)(gsh + flat);
            }
        }

        f32x4 acc[2][2];
#pragma unroll
        for (int mi = 0; mi < 2; ++mi)
#pragma unroll
            for (int ni = 0; ni < 2; ++ni) {
                f32x4 z = {0.f, 0.f, 0.f, 0.f};
                acc[mi][ni] = z;
            }

#pragma unroll
        for (int ks = 0; ks < 2; ++ks)
#pragma unroll
            for (int mi = 0; mi < 2; ++mi)
#pragma unroll
                for (int ni = 0; ni < 2; ++ni)
                    acc[mi][ni] = __builtin_amdgcn_mfma_f32_16x16x32_f16(
                        afrag[mi][ks], wfrag[ni][ks], acc[mi][ni], 0, 0, 0);

        const size_t rowBase = ((size_t)b * NOH + oh) * NOW;

        // Epilogue -> LDS tile. D: col -> o tile idx, kq*4+r -> p.
#pragma unroll
        for (int mi = 0; mi < 2; ++mi) {
            const int p0 = n0 + mi * 16 + kq * 4;
            if (p0 >= NOW) continue;                   // p0==124 idle
            const f32x4 x2v = *(const f32x4*)(x2 + rowBase + p0);
            const bool full = (p0 + 3 < NOW);          // p0==120 -> 2 valid
#pragma unroll
            for (int ni = 0; ni < 2; ++ni) {
                f32x4 res;
#pragma unroll
                for (int r = 0; r < 4; ++r) {
                    float sq = fmaxf(fmaf(-2.f, acc[mi][ni][r], x2v[r] + w2c[ni]), 0.f);
                    res[r] = __expf(-sq * inv2s2);
                }
                float* dst = &outT[(ni * 16 + col) * OSTR + lo * 122 + p0];
                f32x2 lo2 = {res[0], res[1]};
                *(f32x2*)dst = lo2;
                if (full) {
                    f32x2 hi2 = {res[2], res[3]};
                    *(f32x2*)(dst + 2) = hi2;
                }
            }
        }
    }

    __syncthreads();

    // Flush: 32 chunks of 1952B contiguous NT stores; wave w owns 8 chunks.
    if (lane < 61) {
        const size_t base = (((size_t)b * NOC + fgg * 32) * NOH + oh0) * NOW;
#pragma unroll 4
        for (int c = 0; c < 8; ++c) {
            const int o = wave * 8 + c;
            float* gdst = out + base + (size_t)o * NOH * NOW + lane * 4;
#pragma unroll
            for (int j = 0; j < 2; ++j) {
                f32x4 v = *(const f32x4*)&outT[o * OSTR + j * 244 + lane * 4];
                __builtin_nontemporal_store(v, (f32x4*)(gdst + j * 244));
            }
        }
    }
}

extern "C" void kernel_launch(void* const* d_in, const int* in_sizes, int n_in,
                              void* d_out, int out_size, void* d_ws, size_t ws_size,
                              hipStream_t stream) {
    const float* x    = (const float*)d_in[0];
    const float* w    = (const float*)d_in[1];
    const float* stdp = (const float*)d_in[2];
    float* out = (float*)d_out;

    char* ws = (char*)d_ws;
    half_t* gh  = (half_t*)ws;
    half_t* Wh  = (half_t*)(ws + 1048576);
    float*  w2  = (float*)(ws + 1114112);
    float*  x2  = (float*)(ws + 1116160);
    float*  Sg  = (float*)(ws + 3021440);
    half_t* ghs = (half_t*)(ws + 5020288);

    k_gray<<<(NPIX / 4 + 255) / 256, 256, 0, stream>>>(x, gh);
    k_w<<<(NOC + 255) / 256, 256, 0, stream>>>(w, Wh, w2);
    k_shift<<<(NPIX / 8 + 255) / 256, 256, 0, stream>>>(gh, ghs);
    k_rs<<<(NB * NH * NOW + 255) / 256, 256, 0, stream>>>(gh, Sg);
    k_x2<<<(NB * NOH * NOW + 255) / 256, 256, 0, stream>>>(Sg, x2);

    dim3 grid(31, 16, NB);
    k_main<<<grid, 256, 0, stream>>>(ghs, Wh, w2, x2, stdp, out);
}